// Round 1
// baseline (9004.263 us; speedup 1.0000x reference)
//
#include <hip/hip_runtime.h>
#include <cstddef>

// Problem constants
#define Bb 128
#define Tt 512
#define Ii 256
#define Hh 512
#define G4c 2048      // 4*H
#define K1c 768       // I + H   (layer1 fused [x,h] GEMM)
#define K2c 1024      // H + H   (layer2 fused [h1,h2] GEMM)
#define BHc (Bb * Hh) // elements in one h buffer

typedef float    f32x4 __attribute__((ext_vector_type(4)));
typedef _Float16 f16x8 __attribute__((ext_vector_type(8)));
typedef unsigned int u32x4 __attribute__((ext_vector_type(4)));

// ws layout (bytes)
#define OFF_WT1 0u
#define OFF_WT2 3145728u          // 2048*768*2
#define OFF_BC1 7340032u          // +2048*1024*2
#define OFF_BC2 7348224u
#define OFF_H1  7356416u          // 2*128*512*2
#define OFF_H2  7618560u
#define OFF_H2F 7880704u          // 128*512*4
#define OFF_CNT 8142848u
#define OFF_END 8143104u

__device__ __forceinline__ float sigm(float x)  { return 1.0f / (1.0f + __expf(-x)); }
__device__ __forceinline__ float tanhf_(float x){ return 1.0f - 2.0f / (1.0f + __expf(2.0f * x)); }

// group barrier over 64 co-resident blocks, monotonic counter
__device__ __forceinline__ void gbar(unsigned* cnt, unsigned target) {
  __syncthreads();
  if (threadIdx.x == 0) {
    __threadfence();  // release: make h-writes agent-visible
    __hip_atomic_fetch_add(cnt, 1u, __ATOMIC_RELEASE, __HIP_MEMORY_SCOPE_AGENT);
    while (__hip_atomic_load(cnt, __ATOMIC_ACQUIRE, __HIP_MEMORY_SCOPE_AGENT) < target)
      __builtin_amdgcn_s_sleep(1);
    __threadfence();  // acquire: invalidate stale lines before reads
  }
  __syncthreads();
}

// Pack weights: Wt[gatecol][k] fp16, K-major, per-column XOR swizzle baked in.
// Layer1 rows: k<256 -> W_x1[k][gc], else W_h1[k-256][gc]; layer2: W_x2 / W_h2.
__global__ void init_weights(const float* __restrict__ Wx1, const float* __restrict__ Wh1,
                             const float* __restrict__ bx1, const float* __restrict__ bh1,
                             const float* __restrict__ Wx2, const float* __restrict__ Wh2,
                             const float* __restrict__ bx2, const float* __restrict__ bh2,
                             _Float16* __restrict__ Wt1, _Float16* __restrict__ Wt2,
                             float* __restrict__ bc1, float* __restrict__ bc2) {
  const int b = blockIdx.x;
  const int layer = b >> 11;
  const int gc = b & 2047;
  const int tid = threadIdx.x;
  const int swz = (gc & 7) << 3;  // XOR in units of fp16 elements (16B granules)
  if (layer == 0) {
    if (tid == 0) bc1[gc] = bx1[gc] + bh1[gc];
    for (int k = tid; k < K1c; k += 256) {
      const float v = (k < Ii) ? Wx1[k * G4c + gc] : Wh1[(k - Ii) * G4c + gc];
      Wt1[gc * K1c + (k ^ swz)] = (_Float16)v;
    }
  } else {
    if (tid == 0) bc2[gc] = bx2[gc] + bh2[gc];
    for (int k = tid; k < K2c; k += 256) {
      const float v = (k < Hh) ? Wx2[k * G4c + gc] : Wh2[(k - Hh) * G4c + gc];
      Wt2[gc * K2c + (k ^ swz)] = (_Float16)v;
    }
  }
}

__global__ void zero_ws(u32x4* p, int n) {
  const int i = blockIdx.x * blockDim.x + threadIdx.x;
  if (i < n) p[i] = (u32x4){0u, 0u, 0u, 0u};
}

// Persistent cooperative kernel.
// 128 blocks: bid>>6 = layer (0/1); blkL = bid&63; jb = blkL>>1 (16 H-cols at j0=jb*16);
// rh = blkL&1 (batch rows rh*64..+63). Two independent barrier groups (one per rh).
// Epoch e: layer1 computes step t=e (e<512); layer2 computes step t=e-1 (e>=1).
__global__ __launch_bounds__(256, 1) void lstm_main(
    const float* __restrict__ x,
    const _Float16* __restrict__ Wt1, const _Float16* __restrict__ Wt2,
    const float* __restrict__ bc1, const float* __restrict__ bc2,
    _Float16* h1buf, _Float16* h2buf, float* h2f, unsigned* counters,
    const float* __restrict__ Whead, const float* __restrict__ bhead,
    float* __restrict__ out)
{
  extern __shared__ char smem[];
  _Float16* Wl = (_Float16*)smem;

  const int tid  = threadIdx.x;
  const int lane = tid & 63;
  const int wv   = tid >> 6;          // wave 0..3 -> 16-row band
  const int bid  = blockIdx.x;
  const int layer = bid >> 6;
  const int blkL  = bid & 63;
  const int jb = blkL >> 1;
  const int rh = blkL & 1;
  const int j0 = jb << 4;
  const int K  = layer ? K2c : K1c;
  const _Float16* WtG = layer ? Wt2 : Wt1;
  const float* bc = layer ? bc2 : bc1;

  // ---- stage this block's weight slice into LDS (64 gate-cols x K, preswizzled) ----
  {
    const int chunks = K >> 3;  // 16B granules per row
    for (int cl = 0; cl < 64; ++cl) {
      const int gc = ((cl >> 4) << 9) + j0 + (cl & 15);  // gate g=cl>>4, col j0+(cl&15)
      const u32x4* src = (const u32x4*)(WtG + (size_t)gc * K);
      u32x4* dst = (u32x4*)(Wl + cl * K);
      for (int ch = tid; ch < chunks; ch += 256) dst[ch] = src[ch];
    }
  }
  __syncthreads();

  const int c15 = lane & 15;           // MFMA row (A) / col (B,D)
  const int kg  = lane >> 4;           // k-group
  const int arow  = (rh << 6) + (wv << 4) + c15;          // batch row for A frags
  const int wrow0 = (rh << 6) + (wv << 4) + (kg << 2);    // first D row

  const float bias0 = bc[        j0 + c15];
  const float bias1 = bc[ 512 +  j0 + c15];
  const float bias2 = bc[1024 +  j0 + c15];
  const float bias3 = bc[1536 +  j0 + c15];

  // LDS byte offsets: row (g*16+c15), byte (k0*2) ^ ((c15&7)<<4); k0*2 = ks*64 | kg*16
  // split XOR: low bits (4,5) fold into base, bit6 applied per-ks.
  const int mlo = (c15 & 3) << 4;
  const int mhi = (c15 & 4) << 4;
  const int Kb  = K << 1;
  const int kgo = (kg << 4) ^ mlo;
  const int bb0 = (     c15) * Kb + kgo;
  const int bb1 = (16 + c15) * Kb + kgo;
  const int bb2 = (32 + c15) * Kb + kgo;
  const int bb3 = (48 + c15) * Kb + kgo;

  f32x4 cst = {0.f, 0.f, 0.f, 0.f};  // c-state, f32, registers
  unsigned* cnt = counters + rh;

  for (int e = 0; e <= Tt; ++e) {
    const bool active = layer ? (e >= 1) : (e < Tt);
    if (active) {
      f32x4 acc0 = {0.f,0.f,0.f,0.f}, acc1 = {0.f,0.f,0.f,0.f};
      f32x4 acc2 = {0.f,0.f,0.f,0.f}, acc3 = {0.f,0.f,0.f,0.f};
      if (layer == 0) {
        f16x8 af[24];
        // A prefetch: x_t (k 0..255, f32->f16) then h1(e-1) (k 256..767)
        const float* xp = x + (size_t)arow * (Tt * Ii) + (size_t)e * Ii + (kg << 3);
        #pragma unroll
        for (int ks = 0; ks < 8; ++ks) {
          const f32x4 u0 = *(const f32x4*)(xp + (ks << 5));
          const f32x4 u1 = *(const f32x4*)(xp + (ks << 5) + 4);
          f16x8 v;
          v[0] = (_Float16)u0[0]; v[1] = (_Float16)u0[1];
          v[2] = (_Float16)u0[2]; v[3] = (_Float16)u0[3];
          v[4] = (_Float16)u1[0]; v[5] = (_Float16)u1[1];
          v[6] = (_Float16)u1[2]; v[7] = (_Float16)u1[3];
          af[ks] = v;
        }
        const _Float16* hp = h1buf + ((e + 1) & 1) * BHc + arow * Hh + (kg << 3);
        #pragma unroll
        for (int ks = 0; ks < 16; ++ks)
          af[8 + ks] = *(const f16x8*)(hp + (ks << 5));
        #pragma unroll
        for (int ks = 0; ks < 24; ++ks) {
          const int kx = (ks << 6) ^ mhi;
          acc0 = __builtin_amdgcn_mfma_f32_16x16x32_f16(af[ks], *(const f16x8*)(smem + bb0 + kx), acc0, 0, 0, 0);
          acc1 = __builtin_amdgcn_mfma_f32_16x16x32_f16(af[ks], *(const f16x8*)(smem + bb1 + kx), acc1, 0, 0, 0);
          acc2 = __builtin_amdgcn_mfma_f32_16x16x32_f16(af[ks], *(const f16x8*)(smem + bb2 + kx), acc2, 0, 0, 0);
          acc3 = __builtin_amdgcn_mfma_f32_16x16x32_f16(af[ks], *(const f16x8*)(smem + bb3 + kx), acc3, 0, 0, 0);
        }
      } else {
        f16x8 af[32];
        // A prefetch: h1(e-1) (k 0..511) then h2(e-2) (k 512..1023)
        const _Float16* h1p = h1buf + ((e + 1) & 1) * BHc + arow * Hh + (kg << 3);
        const _Float16* h2p = h2buf + (e & 1) * BHc + arow * Hh + (kg << 3);
        #pragma unroll
        for (int ks = 0; ks < 16; ++ks)
          af[ks] = *(const f16x8*)(h1p + (ks << 5));
        #pragma unroll
        for (int ks = 0; ks < 16; ++ks)
          af[16 + ks] = *(const f16x8*)(h2p + (ks << 5));
        #pragma unroll
        for (int ks = 0; ks < 32; ++ks) {
          const int kx = (ks << 6) ^ mhi;
          acc0 = __builtin_amdgcn_mfma_f32_16x16x32_f16(af[ks], *(const f16x8*)(smem + bb0 + kx), acc0, 0, 0, 0);
          acc1 = __builtin_amdgcn_mfma_f32_16x16x32_f16(af[ks], *(const f16x8*)(smem + bb1 + kx), acc1, 0, 0, 0);
          acc2 = __builtin_amdgcn_mfma_f32_16x16x32_f16(af[ks], *(const f16x8*)(smem + bb2 + kx), acc2, 0, 0, 0);
          acc3 = __builtin_amdgcn_mfma_f32_16x16x32_f16(af[ks], *(const f16x8*)(smem + bb3 + kx), acc3, 0, 0, 0);
        }
      }
      // gates -> c,h (D layout: row = kg*4 + r, col = c15)
      float hout[4];
      #pragma unroll
      for (int r = 0; r < 4; ++r) {
        const float iv = sigm(acc0[r] + bias0);
        const float fv = sigm(acc1[r] + bias1);
        const float gv = tanhf_(acc2[r] + bias2);
        const float ov = sigm(acc3[r] + bias3);
        const float cv = fv * cst[r] + iv * gv;
        cst[r] = cv;
        hout[r] = ov * tanhf_(cv);
      }
      _Float16* hw = layer ? (h2buf + ((e + 1) & 1) * BHc) : (h1buf + (e & 1) * BHc);
      #pragma unroll
      for (int r = 0; r < 4; ++r)
        hw[(wrow0 + r) * Hh + j0 + c15] = (_Float16)hout[r];
      if (layer == 1 && e == Tt) {
        #pragma unroll
        for (int r = 0; r < 4; ++r)
          h2f[(wrow0 + r) * Hh + j0 + c15] = hout[r];
      }
    }
    gbar(cnt, 64u * (unsigned)(e + 1));
  }

  // head: out[b][c] = h2_T[b,:] . W_head[:,c] + b_head[c]; one block per row-group
  if (layer == 1 && jb == 0) {
    const int b_ = (rh << 6) + (tid >> 2);
    const int cc = tid & 3;
    const float* hr = h2f + b_ * Hh;
    float s = bhead[cc];
    #pragma unroll 4
    for (int k = 0; k < Hh; k += 4) {
      const f32x4 hv = *(const f32x4*)(hr + k);
      s += hv[0] * Whead[(k + 0) * 4 + cc];
      s += hv[1] * Whead[(k + 1) * 4 + cc];
      s += hv[2] * Whead[(k + 2) * 4 + cc];
      s += hv[3] * Whead[(k + 3) * 4 + cc];
    }
    out[b_ * 4 + cc] = s;
  }
}

extern "C" void kernel_launch(void* const* d_in, const int* in_sizes, int n_in,
                              void* d_out, int out_size, void* d_ws, size_t ws_size,
                              hipStream_t stream) {
  const float* x   = (const float*)d_in[0];
  const float* Wx1 = (const float*)d_in[1];
  const float* bx1 = (const float*)d_in[2];
  const float* Wh1 = (const float*)d_in[3];
  const float* bh1 = (const float*)d_in[4];
  const float* Wx2 = (const float*)d_in[5];
  const float* bx2 = (const float*)d_in[6];
  const float* Wh2 = (const float*)d_in[7];
  const float* bh2 = (const float*)d_in[8];
  const float* Whd = (const float*)d_in[9];
  const float* bhd = (const float*)d_in[10];

  char* ws = (char*)d_ws;
  _Float16* Wt1 = (_Float16*)(ws + OFF_WT1);
  _Float16* Wt2 = (_Float16*)(ws + OFF_WT2);
  float* bc1 = (float*)(ws + OFF_BC1);
  float* bc2 = (float*)(ws + OFF_BC2);
  _Float16* h1b = (_Float16*)(ws + OFF_H1);
  _Float16* h2b = (_Float16*)(ws + OFF_H2);
  float* h2f = (float*)(ws + OFF_H2F);
  unsigned* cnts = (unsigned*)(ws + OFF_CNT);
  float* out = (float*)d_out;

  init_weights<<<4096, 256, 0, stream>>>(Wx1, Wh1, bx1, bh1, Wx2, Wh2, bx2, bh2,
                                         Wt1, Wt2, bc1, bc2);
  {
    u32x4* zp = (u32x4*)(ws + OFF_H1);
    const int n = (int)((OFF_END - OFF_H1) / 16);  // zero h buffers + h2f + counters
    zero_ws<<<(n + 255) / 256, 256, 0, stream>>>(zp, n);
  }
  (void)hipFuncSetAttribute((const void*)lstm_main,
                            hipFuncAttributeMaxDynamicSharedMemorySize, 131072);
  void* args[] = {(void*)&x, (void*)&Wt1, (void*)&Wt2, (void*)&bc1, (void*)&bc2,
                  (void*)&h1b, (void*)&h2b, (void*)&h2f, (void*)&cnts,
                  (void*)&Whd, (void*)&bhd, (void*)&out};
  (void)hipLaunchCooperativeKernel((const void*)lstm_main, dim3(128), dim3(256),
                                   args, 131072, stream);
}

// Round 2
// 4411.408 us; speedup vs baseline: 2.0411x; 2.0411x over previous
//
#include <hip/hip_runtime.h>
#include <cstddef>

// Problem constants
#define Bb 128
#define Tt 512
#define Ii 256
#define Hh 512
#define G4c 2048      // 4*H
#define K1c 768       // I + H   (layer1 fused [x,h] GEMM)
#define K2c 1024      // H + H   (layer2 fused [h1,h2] GEMM)
#define BHc (Bb * Hh) // elements in one h buffer

typedef float    f32x4 __attribute__((ext_vector_type(4)));
typedef _Float16 f16x8 __attribute__((ext_vector_type(8)));
typedef unsigned int u32x4 __attribute__((ext_vector_type(4)));

// ws layout (bytes)
#define OFF_WT1 0u
#define OFF_WT2 3145728u          // 2048*768*2
#define OFF_BC1 7340032u          // +2048*1024*2
#define OFF_BC2 7348224u
#define OFF_H1  7356416u          // 2*128*512*2
#define OFF_H2  7618560u
#define OFF_H2F 7880704u          // 128*512*4
#define OFF_FLG 8142848u          // 128 u32 flags (2 groups of 64)
#define OFF_END 8143360u

__device__ __forceinline__ float sigm(float x)  { return 1.0f / (1.0f + __expf(-x)); }
__device__ __forceinline__ float tanhf_(float x){ return 1.0f - 2.0f / (1.0f + __expf(2.0f * x)); }

// ---- coherent (cross-XCD) memory ops: bypass non-coherent L2 via sc0 sc1 ----
__device__ __forceinline__ void ld_g_f16x8_sc(f16x8& dst, const _Float16* p) {
  asm volatile("global_load_dwordx4 %0, %1, off sc0 sc1"
               : "=v"(dst) : "v"(p) : "memory");
}
__device__ __forceinline__ void ld_g_f32x4(f32x4& dst, const float* p) {
  asm volatile("global_load_dwordx4 %0, %1, off"
               : "=v"(dst) : "v"(p) : "memory");
}
__device__ __forceinline__ void st_g_f16_sc(_Float16* p, _Float16 v) {
  unsigned u = (unsigned)__builtin_bit_cast(unsigned short, v);
  asm volatile("global_store_short %0, %1, off sc0 sc1" :: "v"(p), "v"(u) : "memory");
}
__device__ __forceinline__ void st_g_f32_sc(float* p, float v) {
  asm volatile("global_store_dword %0, %1, off sc0 sc1" :: "v"(p), "v"(v) : "memory");
}
__device__ __forceinline__ void wait_vm0() {
  asm volatile("s_waitcnt vmcnt(0)" ::: "memory");
}

// Flag barrier over the 64 blocks of one rh-group. No cache maintenance:
// relaxed sc1 flag store (own slot, no contention) + wave-0 polls 64 flags.
__device__ __forceinline__ void flag_barrier(unsigned* grp, unsigned* myflag,
                                             int tid, unsigned target) {
  wait_vm0();            // per-wave: drain this wave's sc1 data stores
  __syncthreads();       // all waves drained
  if (tid < 64) {
    if (tid == 0) {
      __hip_atomic_store(myflag, target, __ATOMIC_RELAXED, __HIP_MEMORY_SCOPE_AGENT);
      wait_vm0();        // own flag at coherent point before polling
    }
    unsigned v;
    do {
      v = __hip_atomic_load(grp + tid, __ATOMIC_RELAXED, __HIP_MEMORY_SCOPE_AGENT);
    } while (__any(v < target));
  }
  __syncthreads();
}

// Pack weights: Wt[gatecol][k] fp16, K-major, per-column XOR swizzle baked in.
__global__ void init_weights(const float* __restrict__ Wx1, const float* __restrict__ Wh1,
                             const float* __restrict__ bx1, const float* __restrict__ bh1,
                             const float* __restrict__ Wx2, const float* __restrict__ Wh2,
                             const float* __restrict__ bx2, const float* __restrict__ bh2,
                             _Float16* __restrict__ Wt1, _Float16* __restrict__ Wt2,
                             float* __restrict__ bc1, float* __restrict__ bc2) {
  const int b = blockIdx.x;
  const int layer = b >> 11;
  const int gc = b & 2047;
  const int tid = threadIdx.x;
  const int swz = (gc & 7) << 3;  // XOR in fp16 elements (16B granules)
  if (layer == 0) {
    if (tid == 0) bc1[gc] = bx1[gc] + bh1[gc];
    for (int k = tid; k < K1c; k += 256) {
      const float v = (k < Ii) ? Wx1[k * G4c + gc] : Wh1[(k - Ii) * G4c + gc];
      Wt1[gc * K1c + (k ^ swz)] = (_Float16)v;
    }
  } else {
    if (tid == 0) bc2[gc] = bx2[gc] + bh2[gc];
    for (int k = tid; k < K2c; k += 256) {
      const float v = (k < Hh) ? Wx2[k * G4c + gc] : Wh2[(k - Hh) * G4c + gc];
      Wt2[gc * K2c + (k ^ swz)] = (_Float16)v;
    }
  }
}

__global__ void zero_ws(u32x4* p, int n) {
  const int i = blockIdx.x * blockDim.x + threadIdx.x;
  if (i < n) p[i] = (u32x4){0u, 0u, 0u, 0u};
}

// Persistent cooperative kernel.
// 128 blocks: bid>>6 = layer (0/1); blkL = bid&63; jb = blkL>>1 (16 H-cols);
// rh = blkL&1 (batch rows rh*64..+63). Two independent 64-block flag groups.
// Epoch e: layer1 computes t=e (e<512); layer2 computes t=e-1 (e>=1).
__global__ __launch_bounds__(256, 1) void lstm_main(
    const float* __restrict__ x,
    const _Float16* __restrict__ Wt1, const _Float16* __restrict__ Wt2,
    const float* __restrict__ bc1, const float* __restrict__ bc2,
    _Float16* h1buf, _Float16* h2buf, float* h2f, unsigned* flags,
    const float* __restrict__ Whead, const float* __restrict__ bhead,
    float* __restrict__ out)
{
  extern __shared__ char smem[];
  _Float16* Wl = (_Float16*)smem;

  const int tid  = threadIdx.x;
  const int lane = tid & 63;
  const int wv   = tid >> 6;          // wave 0..3 -> 16-row band
  const int bid  = blockIdx.x;
  const int layer = bid >> 6;
  const int blkL  = bid & 63;
  const int jb = blkL >> 1;
  const int rh = blkL & 1;
  const int j0 = jb << 4;
  const int K  = layer ? K2c : K1c;
  const _Float16* WtG = layer ? Wt2 : Wt1;
  const float* bc = layer ? bc2 : bc1;

  unsigned* grp = flags + (rh << 6);
  unsigned* myflag = grp + (layer << 5) + jb;

  // ---- stage weight slice into LDS (64 gate-cols x K, preswizzled) ----
  {
    const int chunks = K >> 3;  // 16B granules per row
    for (int cl = 0; cl < 64; ++cl) {
      const int gc = ((cl >> 4) << 9) + j0 + (cl & 15);
      const u32x4* src = (const u32x4*)(WtG + (size_t)gc * K);
      u32x4* dst = (u32x4*)(Wl + cl * K);
      for (int ch = tid; ch < chunks; ch += 256) dst[ch] = src[ch];
    }
  }
  __syncthreads();

  const int c15 = lane & 15;           // MFMA row (A) / col (B,D)
  const int kg  = lane >> 4;           // k-group
  const int arow  = (rh << 6) + (wv << 4) + c15;          // batch row for A frags
  const int wrow0 = (rh << 6) + (wv << 4) + (kg << 2);    // first D row

  const float bias0 = bc[        j0 + c15];
  const float bias1 = bc[ 512 +  j0 + c15];
  const float bias2 = bc[1024 +  j0 + c15];
  const float bias3 = bc[1536 +  j0 + c15];

  // LDS byte offsets with baked swizzle
  const int mlo = (c15 & 3) << 4;
  const int mhi = (c15 & 4) << 4;
  const int Kb  = K << 1;
  const int kgo = (kg << 4) ^ mlo;
  const int bb0 = (     c15) * Kb + kgo;
  const int bb1 = (16 + c15) * Kb + kgo;
  const int bb2 = (32 + c15) * Kb + kgo;
  const int bb3 = (48 + c15) * Kb + kgo;

  f32x4 cst = {0.f, 0.f, 0.f, 0.f};  // c-state, f32, registers

  for (int e = 0; e <= Tt; ++e) {
    const bool active = layer ? (e >= 1) : (e < Tt);
    if (active) {
      f32x4 acc0 = {0.f,0.f,0.f,0.f}, acc1 = {0.f,0.f,0.f,0.f};
      f32x4 acc2 = {0.f,0.f,0.f,0.f}, acc3 = {0.f,0.f,0.f,0.f};
      if (layer == 0) {
        // issue ALL A loads (x: cached; h1: coherent) then one wait
        f32x4 xf[16];
        f16x8 af[24];
        const float* xp = x + (size_t)arow * (Tt * Ii) + (size_t)e * Ii + (kg << 3);
        #pragma unroll
        for (int ks = 0; ks < 8; ++ks) {
          ld_g_f32x4(xf[2*ks],   xp + (ks << 5));
          ld_g_f32x4(xf[2*ks+1], xp + (ks << 5) + 4);
        }
        const _Float16* hp = h1buf + ((e + 1) & 1) * BHc + arow * Hh + (kg << 3);
        #pragma unroll
        for (int ks = 0; ks < 16; ++ks)
          ld_g_f16x8_sc(af[8 + ks], hp + (ks << 5));
        wait_vm0();
        __builtin_amdgcn_sched_barrier(0);
        #pragma unroll
        for (int ks = 0; ks < 8; ++ks) {
          f16x8 v;
          v[0] = (_Float16)xf[2*ks][0]; v[1] = (_Float16)xf[2*ks][1];
          v[2] = (_Float16)xf[2*ks][2]; v[3] = (_Float16)xf[2*ks][3];
          v[4] = (_Float16)xf[2*ks+1][0]; v[5] = (_Float16)xf[2*ks+1][1];
          v[6] = (_Float16)xf[2*ks+1][2]; v[7] = (_Float16)xf[2*ks+1][3];
          af[ks] = v;
        }
        #pragma unroll
        for (int ks = 0; ks < 24; ++ks) {
          const int kx = (ks << 6) ^ mhi;
          acc0 = __builtin_amdgcn_mfma_f32_16x16x32_f16(af[ks], *(const f16x8*)(smem + bb0 + kx), acc0, 0, 0, 0);
          acc1 = __builtin_amdgcn_mfma_f32_16x16x32_f16(af[ks], *(const f16x8*)(smem + bb1 + kx), acc1, 0, 0, 0);
          acc2 = __builtin_amdgcn_mfma_f32_16x16x32_f16(af[ks], *(const f16x8*)(smem + bb2 + kx), acc2, 0, 0, 0);
          acc3 = __builtin_amdgcn_mfma_f32_16x16x32_f16(af[ks], *(const f16x8*)(smem + bb3 + kx), acc3, 0, 0, 0);
        }
      } else {
        f16x8 af[32];
        const _Float16* h1p = h1buf + ((e + 1) & 1) * BHc + arow * Hh + (kg << 3);
        const _Float16* h2p = h2buf + (e & 1) * BHc + arow * Hh + (kg << 3);
        #pragma unroll
        for (int ks = 0; ks < 16; ++ks)
          ld_g_f16x8_sc(af[ks], h1p + (ks << 5));
        #pragma unroll
        for (int ks = 0; ks < 16; ++ks)
          ld_g_f16x8_sc(af[16 + ks], h2p + (ks << 5));
        wait_vm0();
        __builtin_amdgcn_sched_barrier(0);
        #pragma unroll
        for (int ks = 0; ks < 32; ++ks) {
          const int kx = (ks << 6) ^ mhi;
          acc0 = __builtin_amdgcn_mfma_f32_16x16x32_f16(af[ks], *(const f16x8*)(smem + bb0 + kx), acc0, 0, 0, 0);
          acc1 = __builtin_amdgcn_mfma_f32_16x16x32_f16(af[ks], *(const f16x8*)(smem + bb1 + kx), acc1, 0, 0, 0);
          acc2 = __builtin_amdgcn_mfma_f32_16x16x32_f16(af[ks], *(const f16x8*)(smem + bb2 + kx), acc2, 0, 0, 0);
          acc3 = __builtin_amdgcn_mfma_f32_16x16x32_f16(af[ks], *(const f16x8*)(smem + bb3 + kx), acc3, 0, 0, 0);
        }
      }
      // gates -> c,h (D layout: row = kg*4 + r, col = c15)
      float hout[4];
      #pragma unroll
      for (int r = 0; r < 4; ++r) {
        const float iv = sigm(acc0[r] + bias0);
        const float fv = sigm(acc1[r] + bias1);
        const float gv = tanhf_(acc2[r] + bias2);
        const float ov = sigm(acc3[r] + bias3);
        const float cv = fv * cst[r] + iv * gv;
        cst[r] = cv;
        hout[r] = ov * tanhf_(cv);
      }
      _Float16* hw = layer ? (h2buf + ((e + 1) & 1) * BHc) : (h1buf + (e & 1) * BHc);
      #pragma unroll
      for (int r = 0; r < 4; ++r)
        st_g_f16_sc(hw + (wrow0 + r) * Hh + j0 + c15, (_Float16)hout[r]);
      if (layer == 1 && e == Tt) {
        #pragma unroll
        for (int r = 0; r < 4; ++r)
          st_g_f32_sc(h2f + (wrow0 + r) * Hh + j0 + c15, hout[r]);
      }
    }
    flag_barrier(grp, myflag, tid, (unsigned)(e + 1));
  }

  // head: out[b][c] = h2_T[b,:] . W_head[:,c] + b_head[c]
  if (layer == 1 && jb == 0) {
    if (tid == 0)
      (void)__hip_atomic_load(grp, __ATOMIC_ACQUIRE, __HIP_MEMORY_SCOPE_AGENT);
    __syncthreads();
    const int b_ = (rh << 6) + (tid >> 2);
    const int cc = tid & 3;
    const float* hr = h2f + b_ * Hh;
    float s = bhead[cc];
    #pragma unroll 4
    for (int k = 0; k < Hh; k += 4) {
      const f32x4 hv = *(const f32x4*)(hr + k);
      s += hv[0] * Whead[(k + 0) * 4 + cc];
      s += hv[1] * Whead[(k + 1) * 4 + cc];
      s += hv[2] * Whead[(k + 2) * 4 + cc];
      s += hv[3] * Whead[(k + 3) * 4 + cc];
    }
    out[b_ * 4 + cc] = s;
  }
}

extern "C" void kernel_launch(void* const* d_in, const int* in_sizes, int n_in,
                              void* d_out, int out_size, void* d_ws, size_t ws_size,
                              hipStream_t stream) {
  const float* x   = (const float*)d_in[0];
  const float* Wx1 = (const float*)d_in[1];
  const float* bx1 = (const float*)d_in[2];
  const float* Wh1 = (const float*)d_in[3];
  const float* bh1 = (const float*)d_in[4];
  const float* Wx2 = (const float*)d_in[5];
  const float* bx2 = (const float*)d_in[6];
  const float* Wh2 = (const float*)d_in[7];
  const float* bh2 = (const float*)d_in[8];
  const float* Whd = (const float*)d_in[9];
  const float* bhd = (const float*)d_in[10];

  char* ws = (char*)d_ws;
  _Float16* Wt1 = (_Float16*)(ws + OFF_WT1);
  _Float16* Wt2 = (_Float16*)(ws + OFF_WT2);
  float* bc1 = (float*)(ws + OFF_BC1);
  float* bc2 = (float*)(ws + OFF_BC2);
  _Float16* h1b = (_Float16*)(ws + OFF_H1);
  _Float16* h2b = (_Float16*)(ws + OFF_H2);
  float* h2f = (float*)(ws + OFF_H2F);
  unsigned* flg = (unsigned*)(ws + OFF_FLG);
  float* out = (float*)d_out;

  init_weights<<<4096, 256, 0, stream>>>(Wx1, Wh1, bx1, bh1, Wx2, Wh2, bx2, bh2,
                                         Wt1, Wt2, bc1, bc2);
  {
    u32x4* zp = (u32x4*)(ws + OFF_H1);
    const int n = (int)((OFF_END - OFF_H1) / 16);  // zero h buffers + h2f + flags
    zero_ws<<<(n + 255) / 256, 256, 0, stream>>>(zp, n);
  }
  (void)hipFuncSetAttribute((const void*)lstm_main,
                            hipFuncAttributeMaxDynamicSharedMemorySize, 131072);
  void* args[] = {(void*)&x, (void*)&Wt1, (void*)&Wt2, (void*)&bc1, (void*)&bc2,
                  (void*)&h1b, (void*)&h2b, (void*)&h2f, (void*)&flg,
                  (void*)&Whd, (void*)&bhd, (void*)&out};
  (void)hipLaunchCooperativeKernel((const void*)lstm_main, dim3(128), dim3(256),
                                   args, 131072, stream);
}